// Round 7
// baseline (136.625 us; speedup 1.0000x reference)
//
#include <hip/hip_runtime.h>
#include <cstdint>
#include <cstddef>

#define BB 16
#define NTOT 1048576
#define SS 32
#define SEG 32768
#define DIM 256
#define VW 512        // verifier bitmap words (16384 bits)

// ---------------- workspace layout (bytes), sizes derived explicitly ----------
// histX : BB*SS*256*4 = 524,288      [0, 524288)
// histY : 524,288                    [524288, 1048576)   dead after k_shifts
// BM0   : 16*8segs*4parts*512*4 = 1,048,576  [1048576, 2097152) dead after scan0
// BM1   : 16*22segs*2parts*512*4 = 1,441,792 [0, 1441792) aliases dead hist+BM0
#define OFF_HX   0u
#define OFF_HY   524288u
#define OFF_BM0  1048576u
#define OFF_BM1  0u
#define OFF_AX   2097152u            // BB*SS*4 = 2048
#define OFF_AY   2099200u            // 2048
#define OFF_PR   2101248u            // 2048
#define OFF_ACT  2103296u            // 1024
#define OFF_TOT  2104320u            // 1024
#define OFF_VER  2105344u            // BB*VW*4 = 32768 -> end 2,138,112 (~2.14 MB)

__device__ __forceinline__ int clamp255(int v) {
    return v < 0 ? 0 : (v > 255 ? 255 : v);
}

// ---------------- K1: per-THREAD-column private histograms ---------------------
// grid = BB*SS*2 (1024 blocks), 64 threads. Block (b,s,arr) histograms one
// segment of one array. LDS ph[256][64]: address of ph[v][t] has bank t%32 —
// DATA-INDEPENDENT 2-way (free), zero same-address collisions. ds_add_u32 is
// fire-and-forget (no return) -> no latency chain. Direct hist write (no
// memset, no global atomics).
__global__ __launch_bounds__(64) void k_hist2(const int* __restrict__ xs,
                                              const int* __restrict__ ys,
                                              uint32_t* __restrict__ histX,
                                              uint32_t* __restrict__ histY) {
    int blk = blockIdx.x;
    int arr = blk & 1;
    int s = (blk >> 1) & 31;
    int b = blk >> 6;
    const int* src = arr ? ys : xs;
    uint32_t* dst = arr ? histY : histX;
    __shared__ uint32_t ph[256][64];      // 64 KB
    int t = threadIdx.x;
    for (int v = 0; v < 256; ++v) ph[v][t] = 0u;
    __syncthreads();
    const int4* p4 = (const int4*)(src + (size_t)b * NTOT + (size_t)s * SEG);
#pragma unroll 4
    for (int i = 0; i < 128; ++i) {       // 128 iters * 64 thr * 4 = 32768 els
        int4 v = p4[i * 64 + t];
        atomicAdd(&ph[v.x][t], 1u);
        atomicAdd(&ph[v.y][t], 1u);
        atomicAdd(&ph[v.z][t], 1u);
        atomicAdd(&ph[v.w][t], 1u);
    }
    __syncthreads();
    // merge: thread t sums bins t, t+64, t+128, t+192; rotated column read
    // (jj = (j+t)&63) makes bank = (j+t)%32 -> conflict-free.
    uint32_t* o = dst + (size_t)(b * SS + s) * 256;
#pragma unroll
    for (int k = 0; k < 4; ++k) {
        int v = t + k * 64;
        uint32_t sum = 0u;
        for (int j = 0; j < 64; ++j) {
            int jj = (j + t) & 63;
            sum += ph[v][jj];
        }
        o[v] = sum;
    }
}

// ---------------- K2: wave-parallel stats -> clip -> blur -> centroid -> shifts
// 32 blocks (b,axis) x 256 thr (4 waves). One row / one centroid per wave,
// shfl-butterfly reductions. Pooled std (mean=128 exact, divisor 8191).
// Clip folded into blur reads (exact).
__global__ __launch_bounds__(256) void k_shifts(const uint32_t* __restrict__ histX,
                                                const uint32_t* __restrict__ histY,
                                                const float* __restrict__ blurk,
                                                int* __restrict__ alignedX,
                                                int* __restrict__ alignedY) {
    int blk = blockIdx.x;          // 0..31 : b*2 + axis
    int b = blk >> 1, axis = blk & 1;
    const uint32_t* hist = (axis == 0 ? histX : histY) + (size_t)b * SS * DIM;
    int* out = (axis == 0 ? alignedX : alignedY) + b * SS;

    __shared__ float vals[SS][DIM];
    __shared__ double wsq[4];
    __shared__ float mrow[SS];
    int t = threadIdx.x;
    int w = t >> 6, lane = t & 63;
    int c0 = lane << 2;                       // 4 columns per lane

    double lsq = 0.0;
    for (int r = w; r < SS; r += 4) {
        uint4 u = *(const uint4*)(hist + r * DIM + c0);
        float v0 = (float)u.x, v1 = (float)u.y, v2 = (float)u.z, v3 = (float)u.w;
        vals[r][c0 + 0] = v0; vals[r][c0 + 1] = v1;
        vals[r][c0 + 2] = v2; vals[r][c0 + 3] = v3;
        double d0 = (double)v0 - 128.0, d1 = (double)v1 - 128.0;
        double d2 = (double)v2 - 128.0, d3 = (double)v3 - 128.0;
        lsq += d0 * d0 + d1 * d1 + d2 * d2 + d3 * d3;
    }
    for (int o = 32; o > 0; o >>= 1) lsq += __shfl_xor(lsq, o, 64);
    if (lane == 0) wsq[w] = lsq;
    __syncthreads();
    float s2 = (float)(wsq[0] + wsq[1] + wsq[2] + wsq[3]);   // exact integer
    float sd = sqrtf(s2 / 8191.0f);                          // ddof=1, pooled
    float thr = 128.0f + 3.0f * sd;

    float k00 = blurk[0], k01 = blurk[1], k02 = blurk[2];
    float k10 = blurk[3], k11 = blurk[4], k12 = blurk[5];
    float k20 = blurk[6], k21 = blurk[7], k22 = blurk[8];

#define V(r, c) fminf(vals[r][c], thr)
    for (int s = w; s < SS; s += 4) {
        double dot = 0.0;
#pragma unroll
        for (int j = 0; j < 4; ++j) {
            int c = c0 + j;
            int cm = c - 1, cp = c + 1;
            bool cml = (cm >= 0), cpl = (cp < DIM);
            float bsum = 0.0f;
            if (s - 1 >= 0) {
                if (cml) bsum += k00 * V(s - 1, cm);
                bsum += k01 * V(s - 1, c);
                if (cpl) bsum += k02 * V(s - 1, cp);
            }
            if (cml) bsum += k10 * V(s, cm);
            bsum += k11 * V(s, c);
            if (cpl) bsum += k12 * V(s, cp);
            if (s + 1 < SS) {
                if (cml) bsum += k20 * V(s + 1, cm);
                bsum += k21 * V(s + 1, c);
                if (cpl) bsum += k22 * V(s + 1, cp);
            }
            dot += (double)bsum * (double)c;
        }
        for (int o = 32; o > 0; o >>= 1) dot += __shfl_xor(dot, o, 64);
        if (lane == 0) mrow[s] = (float)(dot / 32768.0);
    }
#undef V
    __syncthreads();

    if (t < SS) {
        float start = mrow[2];                    // START = 2
        float a = mrow[t] - start;
        float c = 128.0f - start;                 // dimlen//2 - start
        out[t] = (int)rintf(a - c);               // round half-to-even
    }
}

// ---------------- K3: partial verifier bitmaps for a segment group -------------
__global__ __launch_bounds__(256) void k_bitmap_g(const int* __restrict__ xs,
                                                  const int* __restrict__ ys,
                                                  const int* __restrict__ aX,
                                                  const int* __restrict__ aY,
                                                  const int* __restrict__ active,
                                                  uint32_t* __restrict__ bmp,
                                                  int first_seg, int nseg,
                                                  int parts, int check_active) {
    int blk = blockIdx.x;
    int p = blk % parts;
    int sl = (blk / parts) % nseg;
    int b = blk / (parts * nseg);
    if (check_active && !active[b]) return;
    int s = first_seg + sl;
    int shx = aX[b * SS + s];
    int shy = aY[b * SS + s];
    __shared__ uint32_t bm[VW];
    int t = threadIdx.x;
    bm[t] = 0u; bm[t + 256] = 0u;
    __syncthreads();
    size_t base = (size_t)b * NTOT + (size_t)s * SEG + (size_t)p * (SEG / parts);
    const int4* x4 = (const int4*)(xs + base);
    const int4* y4 = (const int4*)(ys + base);
    int iters = SEG / (parts * 1024);
    for (int i = 0; i < iters; ++i) {
        int4 xv = x4[i * 256 + t];
        int4 yv = y4[i * 256 + t];
#define DOV(xc, yc) { int xf = clamp255((xc) - shx); int yf = clamp255((yc) - shy); \
                      int iv = (xf >> 1) + ((yf >> 1) << 7); \
                      atomicOr(&bm[iv >> 5], 1u << (iv & 31)); }
        DOV(xv.x, yv.x) DOV(xv.y, yv.y) DOV(xv.z, yv.z) DOV(xv.w, yv.w)
#undef DOV
    }
    __syncthreads();
    uint32_t* outp = bmp + ((size_t)(b * nseg + sl) * parts + p) * VW;
    outp[t] = bm[t];
    outp[t + 256] = bm[t + 256];
}

// ---------------- K4: sequential verifier scan over one group ------------------
__global__ __launch_bounds__(256) void k_scan_g(const uint32_t* __restrict__ bmp,
                                                int* __restrict__ proceed,
                                                uint32_t* __restrict__ ver_state,
                                                int* __restrict__ total_state,
                                                int* __restrict__ active_state,
                                                int first_seg, int nseg,
                                                int parts, int do_init) {
    int b = blockIdx.x;                   // 0..15
    int t = threadIdx.x;
    __shared__ uint32_t ver[VW];
    __shared__ int wred[4];
    __shared__ int sh_flag;
    __shared__ int sh_total;

    for (int i = t; i < nseg; i += 256) proceed[b * SS + first_seg + i] = 0;

    int active = do_init ? 1 : active_state[b];
    if (!active) {
        if (t == 0) active_state[b] = 0;
        return;
    }

    const uint32_t* base = bmp + (size_t)b * nseg * parts * VW;
    int wid = t >> 6, lane = t & 63;
    int start_local;

    if (do_init) {
        uint32_t w0 = 0, w1 = 0;
        for (int p = 0; p < parts; ++p) {
            w0 |= base[(size_t)p * VW + t];
            w1 |= base[(size_t)p * VW + t + 256];
        }
        ver[t] = w0; ver[t + 256] = w1;
        int c = __popc(w0) + __popc(w1);
        for (int o = 32; o > 0; o >>= 1) c += __shfl_down(c, o, 64);
        if (lane == 0) wred[wid] = c;
        __syncthreads();
        if (t == 0) {
            sh_total = wred[0] + wred[1] + wred[2] + wred[3];
            proceed[b * SS + first_seg] = 1;   // START segment
        }
        start_local = 1;
    } else {
        ver[t] = ver_state[(size_t)b * VW + t];
        ver[t + 256] = ver_state[(size_t)b * VW + t + 256];
        if (t == 0) sh_total = total_state[b];
        start_local = 0;
    }
    __syncthreads();

    for (int sl = start_local; sl < nseg; ++sl) {
        uint32_t w0 = 0, w1 = 0;
        for (int p = 0; p < parts; ++p) {
            w0 |= base[(size_t)(sl * parts + p) * VW + t];
            w1 |= base[(size_t)(sl * parts + p) * VW + t + 256];
        }
        int c = __popc(w0 & ~ver[t]) + __popc(w1 & ~ver[t + 256]);
        for (int o = 32; o > 0; o >>= 1) c += __shfl_down(c, o, 64);
        if (lane == 0) wred[wid] = c;
        __syncthreads();
        if (t == 0) {
            int newly = wred[0] + wred[1] + wred[2] + wred[3];
            int total = sh_total + newly;
            float ratio = (float)newly / (float)total;
            int f = (ratio >= 0.01f) ? 1 : 0;
            sh_flag = f;
            if (f) {
                sh_total = total;
                proceed[b * SS + first_seg + sl] = 1;
            }
        }
        __syncthreads();
        if (!sh_flag) { active = 0; break; }
        ver[t] |= w0;
        ver[t + 256] |= w1;
        __syncthreads();
    }

    ver_state[(size_t)b * VW + t] = ver[t];
    ver_state[(size_t)b * VW + t + 256] = ver[t + 256];
    if (t == 0) {
        total_state[b] = sh_total;
        active_state[b] = active;
    }
}

// ---------------- K5: per-batch-EIGHTH LDS accumulation ------------------------
// 8 blocks per batch (128 blocks); each owns y-rows [oct*32, oct*32+32).
// Packed u16 counts in 16 KB LDS; atomics per block cut 4x vs half-split.
// Plain coalesced stores cover all cells (no d_out memset).
__global__ __launch_bounds__(1024) void k_accum3(const int* __restrict__ xs,
                                                 const int* __restrict__ ys,
                                                 const int* __restrict__ aX,
                                                 const int* __restrict__ aY,
                                                 const int* __restrict__ proceed,
                                                 float* __restrict__ out) {
    int b = blockIdx.x >> 3, oct = blockIdx.x & 7;    // 128 blocks
    __shared__ uint32_t acc[4096];                    // 8192 u16 cells (32x256)
    int t = threadIdx.x;
    for (int i = t; i < 4096; i += 1024) acc[i] = 0u;
    __syncthreads();
    int ybase = oct << 5;
    for (int s = 2; s < SS; ++s) {
        if (!proceed[b * SS + s]) continue;
        int shx = aX[b * SS + s];
        int shy = aY[b * SS + s];
        const int4* x4 = (const int4*)(xs + (size_t)b * NTOT + (size_t)s * SEG);
        const int4* y4 = (const int4*)(ys + (size_t)b * NTOT + (size_t)s * SEG);
        for (int i = 0; i < 8; ++i) {
            int4 xv = x4[i * 1024 + t];
            int4 yv = y4[i * 1024 + t];
#define DOC(xc, yc) { int xf = clamp255((xc) - shx); int yf = clamp255((yc) - shy); \
                      if ((yf >> 5) == oct) { \
                          int cell = xf + ((yf - ybase) << 8); \
                          atomicAdd(&acc[cell >> 1], 1u << ((cell & 1) << 4)); } }
            DOC(xv.x, yv.x) DOC(xv.y, yv.y) DOC(xv.z, yv.z) DOC(xv.w, yv.w)
#undef DOC
        }
    }
    __syncthreads();
    float2* ob = (float2*)(out + (size_t)b * 65536 + ((size_t)oct << 13));
    for (int i = t; i < 4096; i += 1024) {
        uint32_t w = acc[i];
        ob[i] = make_float2((float)(w & 0xFFFFu), (float)(w >> 16));
    }
}

extern "C" void kernel_launch(void* const* d_in, const int* in_sizes, int n_in,
                              void* d_out, int out_size, void* d_ws, size_t ws_size,
                              hipStream_t stream) {
    const int* xs = (const int*)d_in[0];
    const int* ys = (const int*)d_in[1];
    const float* blurk = (const float*)d_in[2];
    float* out = (float*)d_out;

    uint8_t* ws = (uint8_t*)d_ws;
    uint32_t* histX = (uint32_t*)(ws + OFF_HX);
    uint32_t* histY = (uint32_t*)(ws + OFF_HY);
    int* aX = (int*)(ws + OFF_AX);
    int* aY = (int*)(ws + OFF_AY);
    int* proceed = (int*)(ws + OFF_PR);
    int* active = (int*)(ws + OFF_ACT);
    int* total = (int*)(ws + OFF_TOT);
    uint32_t* ver = (uint32_t*)(ws + OFF_VER);
    uint32_t* bm0 = (uint32_t*)(ws + OFF_BM0);
    uint32_t* bm1 = (uint32_t*)(ws + OFF_BM1);

    k_hist2<<<BB * SS * 2, 64, 0, stream>>>(xs, ys, histX, histY);
    k_shifts<<<BB * 2, 256, 0, stream>>>(histX, histY, blurk, aX, aY);

    // group 0: segments 2..9, 4 partials (init; no active check)
    k_bitmap_g<<<BB * 8 * 4, 256, 0, stream>>>(xs, ys, aX, aY, active,
                                               bm0, 2, 8, 4, 0);
    k_scan_g<<<BB, 256, 0, stream>>>(bm0, proceed, ver, total, active, 2, 8, 4, 1);

    // group 1: segments 10..31, 2 partials (active-gated; expected no-op).
    k_bitmap_g<<<BB * 22 * 2, 256, 0, stream>>>(xs, ys, aX, aY, active,
                                                bm1, 10, 22, 2, 1);
    k_scan_g<<<BB, 256, 0, stream>>>(bm1, proceed, ver, total, active, 10, 22, 2, 0);

    k_accum3<<<BB * 8, 1024, 0, stream>>>(xs, ys, aX, aY, proceed, out);
}

// Round 8
// 85.666 us; speedup vs baseline: 1.5949x; 1.5949x over previous
//
#include <hip/hip_runtime.h>
#include <cstdint>
#include <cstddef>

#define BB 16
#define NTOT 1048576
#define SS 32
#define SEG 32768
#define DIM 256
#define VW 512        // verifier bitmap words (16384 bits)

// ---------------- workspace layout (bytes), sizes derived explicitly ----------
// histX : BB*SS*256*4 = 524,288      [0, 524288)
// histY : 524,288                    [524288, 1048576)   dead after k_shifts
// BM0   : 16*8segs*4parts*512*4 = 1,048,576  [1048576, 2097152) dead after scan0
// BM1   : 16*22segs*2parts*512*4 = 1,441,792 [0, 1441792) aliases dead hist+BM0
#define OFF_HX   0u
#define OFF_HY   524288u
#define OFF_BM0  1048576u
#define OFF_BM1  0u
#define OFF_AX   2097152u            // BB*SS*4 = 2048
#define OFF_AY   2099200u            // 2048
#define OFF_PR   2101248u            // 2048
#define OFF_ACT  2103296u            // 1024
#define OFF_TOT  2104320u            // 1024
#define OFF_VER  2105344u            // BB*VW*4 = 32768 -> end 2,138,112 (~2.14 MB)

__device__ __forceinline__ int clamp255(int v) {
    return v < 0 ? 0 : (v > 255 ? 255 : v);
}

// ---------------- K1: conflict-free column-private histograms ------------------
// grid = BB*SS*4parts*2arr = 4096 blocks x 256 thr. ph[256][32], column = t&31:
// bank = (v*32 + t%32)%32 = t%32 — DATA-INDEPENDENT, 2 lanes/bank (free),
// no same-address serialization. 32 KB LDS -> 5 blocks/CU (20 waves/CU).
// Merge: thread t owns bin t, rotated column read, 1 global atomic/thread.
__global__ __launch_bounds__(256) void k_hist3(const int* __restrict__ xs,
                                               const int* __restrict__ ys,
                                               uint32_t* __restrict__ histX,
                                               uint32_t* __restrict__ histY) {
    int blk = blockIdx.x;
    int arr = blk & 1;
    int p = (blk >> 1) & 3;
    int s = (blk >> 3) & 31;
    int b = blk >> 8;
    const int* src = arr ? ys : xs;
    uint32_t* dst = arr ? histY : histX;
    __shared__ uint32_t ph[256][32];      // 32 KB
    int t = threadIdx.x;
    uint32_t* phl = (uint32_t*)ph;
#pragma unroll
    for (int i = 0; i < 32; ++i) phl[t + i * 256] = 0u;   // bank t%32, free
    __syncthreads();
    int c = t & 31;
    const int4* p4 = (const int4*)(src + (size_t)b * NTOT + (size_t)s * SEG
                                   + (size_t)p * 8192);
#pragma unroll 8
    for (int i = 0; i < 8; ++i) {         // 8 * 256 * 4 = 8192 elements
        int4 v = p4[i * 256 + t];
        atomicAdd(&ph[v.x][c], 1u);
        atomicAdd(&ph[v.y][c], 1u);
        atomicAdd(&ph[v.z][c], 1u);
        atomicAdd(&ph[v.w][c], 1u);
    }
    __syncthreads();
    uint32_t sum = 0u;
#pragma unroll
    for (int j = 0; j < 32; ++j)
        sum += ph[t][(j + t) & 31];       // bank (j+t)%32 rotated, free
    atomicAdd(&dst[(size_t)(b * SS + s) * 256 + t], sum);
}

// ---------------- K2: wave-parallel stats -> clip -> blur -> centroid -> shifts
// 32 blocks (b,axis) x 256 thr (4 waves). One row / one centroid per wave,
// shfl-butterfly reductions. Pooled std (mean=128 exact, divisor 8191).
// Clip folded into blur reads (exact).
__global__ __launch_bounds__(256) void k_shifts(const uint32_t* __restrict__ histX,
                                                const uint32_t* __restrict__ histY,
                                                const float* __restrict__ blurk,
                                                int* __restrict__ alignedX,
                                                int* __restrict__ alignedY) {
    int blk = blockIdx.x;          // 0..31 : b*2 + axis
    int b = blk >> 1, axis = blk & 1;
    const uint32_t* hist = (axis == 0 ? histX : histY) + (size_t)b * SS * DIM;
    int* out = (axis == 0 ? alignedX : alignedY) + b * SS;

    __shared__ float vals[SS][DIM];
    __shared__ double wsq[4];
    __shared__ float mrow[SS];
    int t = threadIdx.x;
    int w = t >> 6, lane = t & 63;
    int c0 = lane << 2;                       // 4 columns per lane

    double lsq = 0.0;
    for (int r = w; r < SS; r += 4) {
        uint4 u = *(const uint4*)(hist + r * DIM + c0);
        float v0 = (float)u.x, v1 = (float)u.y, v2 = (float)u.z, v3 = (float)u.w;
        vals[r][c0 + 0] = v0; vals[r][c0 + 1] = v1;
        vals[r][c0 + 2] = v2; vals[r][c0 + 3] = v3;
        double d0 = (double)v0 - 128.0, d1 = (double)v1 - 128.0;
        double d2 = (double)v2 - 128.0, d3 = (double)v3 - 128.0;
        lsq += d0 * d0 + d1 * d1 + d2 * d2 + d3 * d3;
    }
    for (int o = 32; o > 0; o >>= 1) lsq += __shfl_xor(lsq, o, 64);
    if (lane == 0) wsq[w] = lsq;
    __syncthreads();
    float s2 = (float)(wsq[0] + wsq[1] + wsq[2] + wsq[3]);   // exact integer
    float sd = sqrtf(s2 / 8191.0f);                          // ddof=1, pooled
    float thr = 128.0f + 3.0f * sd;

    float k00 = blurk[0], k01 = blurk[1], k02 = blurk[2];
    float k10 = blurk[3], k11 = blurk[4], k12 = blurk[5];
    float k20 = blurk[6], k21 = blurk[7], k22 = blurk[8];

#define V(r, c) fminf(vals[r][c], thr)
    for (int s = w; s < SS; s += 4) {
        double dot = 0.0;
#pragma unroll
        for (int j = 0; j < 4; ++j) {
            int c = c0 + j;
            int cm = c - 1, cp = c + 1;
            bool cml = (cm >= 0), cpl = (cp < DIM);
            float bsum = 0.0f;
            if (s - 1 >= 0) {
                if (cml) bsum += k00 * V(s - 1, cm);
                bsum += k01 * V(s - 1, c);
                if (cpl) bsum += k02 * V(s - 1, cp);
            }
            if (cml) bsum += k10 * V(s, cm);
            bsum += k11 * V(s, c);
            if (cpl) bsum += k12 * V(s, cp);
            if (s + 1 < SS) {
                if (cml) bsum += k20 * V(s + 1, cm);
                bsum += k21 * V(s + 1, c);
                if (cpl) bsum += k22 * V(s + 1, cp);
            }
            dot += (double)bsum * (double)c;
        }
        for (int o = 32; o > 0; o >>= 1) dot += __shfl_xor(dot, o, 64);
        if (lane == 0) mrow[s] = (float)(dot / 32768.0);
    }
#undef V
    __syncthreads();

    if (t < SS) {
        float start = mrow[2];                    // START = 2
        float a = mrow[t] - start;
        float c = 128.0f - start;                 // dimlen//2 - start
        out[t] = (int)rintf(a - c);               // round half-to-even
    }
}

// ---------------- K3: partial verifier bitmaps for a segment group -------------
__global__ __launch_bounds__(256) void k_bitmap_g(const int* __restrict__ xs,
                                                  const int* __restrict__ ys,
                                                  const int* __restrict__ aX,
                                                  const int* __restrict__ aY,
                                                  const int* __restrict__ active,
                                                  uint32_t* __restrict__ bmp,
                                                  int first_seg, int nseg,
                                                  int parts, int check_active) {
    int blk = blockIdx.x;
    int p = blk % parts;
    int sl = (blk / parts) % nseg;
    int b = blk / (parts * nseg);
    if (check_active && !active[b]) return;
    int s = first_seg + sl;
    int shx = aX[b * SS + s];
    int shy = aY[b * SS + s];
    __shared__ uint32_t bm[VW];
    int t = threadIdx.x;
    bm[t] = 0u; bm[t + 256] = 0u;
    __syncthreads();
    size_t base = (size_t)b * NTOT + (size_t)s * SEG + (size_t)p * (SEG / parts);
    const int4* x4 = (const int4*)(xs + base);
    const int4* y4 = (const int4*)(ys + base);
    int iters = SEG / (parts * 1024);
    for (int i = 0; i < iters; ++i) {
        int4 xv = x4[i * 256 + t];
        int4 yv = y4[i * 256 + t];
#define DOV(xc, yc) { int xf = clamp255((xc) - shx); int yf = clamp255((yc) - shy); \
                      int iv = (xf >> 1) + ((yf >> 1) << 7); \
                      atomicOr(&bm[iv >> 5], 1u << (iv & 31)); }
        DOV(xv.x, yv.x) DOV(xv.y, yv.y) DOV(xv.z, yv.z) DOV(xv.w, yv.w)
#undef DOV
    }
    __syncthreads();
    uint32_t* outp = bmp + ((size_t)(b * nseg + sl) * parts + p) * VW;
    outp[t] = bm[t];
    outp[t + 256] = bm[t + 256];
}

// ---------------- K4: sequential verifier scan over one group ------------------
__global__ __launch_bounds__(256) void k_scan_g(const uint32_t* __restrict__ bmp,
                                                int* __restrict__ proceed,
                                                uint32_t* __restrict__ ver_state,
                                                int* __restrict__ total_state,
                                                int* __restrict__ active_state,
                                                int first_seg, int nseg,
                                                int parts, int do_init) {
    int b = blockIdx.x;                   // 0..15
    int t = threadIdx.x;
    __shared__ uint32_t ver[VW];
    __shared__ int wred[4];
    __shared__ int sh_flag;
    __shared__ int sh_total;

    for (int i = t; i < nseg; i += 256) proceed[b * SS + first_seg + i] = 0;

    int active = do_init ? 1 : active_state[b];
    if (!active) {
        if (t == 0) active_state[b] = 0;
        return;
    }

    const uint32_t* base = bmp + (size_t)b * nseg * parts * VW;
    int wid = t >> 6, lane = t & 63;
    int start_local;

    if (do_init) {
        uint32_t w0 = 0, w1 = 0;
        for (int p = 0; p < parts; ++p) {
            w0 |= base[(size_t)p * VW + t];
            w1 |= base[(size_t)p * VW + t + 256];
        }
        ver[t] = w0; ver[t + 256] = w1;
        int c = __popc(w0) + __popc(w1);
        for (int o = 32; o > 0; o >>= 1) c += __shfl_down(c, o, 64);
        if (lane == 0) wred[wid] = c;
        __syncthreads();
        if (t == 0) {
            sh_total = wred[0] + wred[1] + wred[2] + wred[3];
            proceed[b * SS + first_seg] = 1;   // START segment
        }
        start_local = 1;
    } else {
        ver[t] = ver_state[(size_t)b * VW + t];
        ver[t + 256] = ver_state[(size_t)b * VW + t + 256];
        if (t == 0) sh_total = total_state[b];
        start_local = 0;
    }
    __syncthreads();

    for (int sl = start_local; sl < nseg; ++sl) {
        uint32_t w0 = 0, w1 = 0;
        for (int p = 0; p < parts; ++p) {
            w0 |= base[(size_t)(sl * parts + p) * VW + t];
            w1 |= base[(size_t)(sl * parts + p) * VW + t + 256];
        }
        int c = __popc(w0 & ~ver[t]) + __popc(w1 & ~ver[t + 256]);
        for (int o = 32; o > 0; o >>= 1) c += __shfl_down(c, o, 64);
        if (lane == 0) wred[wid] = c;
        __syncthreads();
        if (t == 0) {
            int newly = wred[0] + wred[1] + wred[2] + wred[3];
            int total = sh_total + newly;
            float ratio = (float)newly / (float)total;
            int f = (ratio >= 0.01f) ? 1 : 0;
            sh_flag = f;
            if (f) {
                sh_total = total;
                proceed[b * SS + first_seg + sl] = 1;
            }
        }
        __syncthreads();
        if (!sh_flag) { active = 0; break; }
        ver[t] |= w0;
        ver[t + 256] |= w1;
        __syncthreads();
    }

    ver_state[(size_t)b * VW + t] = ver[t];
    ver_state[(size_t)b * VW + t + 256] = ver[t + 256];
    if (t == 0) {
        total_state[b] = sh_total;
        active_state[b] = active;
    }
}

// ---------------- K5: per-batch-half LDS accumulation --------------------------
// 2 blocks per batch; each owns y-rows [half*128, half*128+128). Packed u16
// counts in 64 KB LDS; plain coalesced stores cover all cells (no d_out memset).
__global__ __launch_bounds__(1024) void k_accum2(const int* __restrict__ xs,
                                                 const int* __restrict__ ys,
                                                 const int* __restrict__ aX,
                                                 const int* __restrict__ aY,
                                                 const int* __restrict__ proceed,
                                                 float* __restrict__ out) {
    int b = blockIdx.x >> 1, half = blockIdx.x & 1;   // 32 blocks
    __shared__ uint32_t acc[16384];                   // 32768 u16 cells (128x256)
    int t = threadIdx.x;
    for (int i = t; i < 16384; i += 1024) acc[i] = 0u;
    __syncthreads();
    int ybase = half << 7;
    for (int s = 2; s < SS; ++s) {
        if (!proceed[b * SS + s]) continue;
        int shx = aX[b * SS + s];
        int shy = aY[b * SS + s];
        const int4* x4 = (const int4*)(xs + (size_t)b * NTOT + (size_t)s * SEG);
        const int4* y4 = (const int4*)(ys + (size_t)b * NTOT + (size_t)s * SEG);
        for (int i = 0; i < 8; ++i) {
            int4 xv = x4[i * 1024 + t];
            int4 yv = y4[i * 1024 + t];
#define DOC(xc, yc) { int xf = clamp255((xc) - shx); int yf = clamp255((yc) - shy); \
                      if ((yf >> 7) == half) { \
                          int cell = xf + ((yf - ybase) << 8); \
                          atomicAdd(&acc[cell >> 1], 1u << ((cell & 1) << 4)); } }
            DOC(xv.x, yv.x) DOC(xv.y, yv.y) DOC(xv.z, yv.z) DOC(xv.w, yv.w)
#undef DOC
        }
    }
    __syncthreads();
    float2* ob = (float2*)(out + (size_t)b * 65536 + ((size_t)half << 15));
    for (int i = t; i < 16384; i += 1024) {
        uint32_t w = acc[i];
        ob[i] = make_float2((float)(w & 0xFFFFu), (float)(w >> 16));
    }
}

extern "C" void kernel_launch(void* const* d_in, const int* in_sizes, int n_in,
                              void* d_out, int out_size, void* d_ws, size_t ws_size,
                              hipStream_t stream) {
    const int* xs = (const int*)d_in[0];
    const int* ys = (const int*)d_in[1];
    const float* blurk = (const float*)d_in[2];
    float* out = (float*)d_out;

    uint8_t* ws = (uint8_t*)d_ws;
    uint32_t* histX = (uint32_t*)(ws + OFF_HX);
    uint32_t* histY = (uint32_t*)(ws + OFF_HY);
    int* aX = (int*)(ws + OFF_AX);
    int* aY = (int*)(ws + OFF_AY);
    int* proceed = (int*)(ws + OFF_PR);
    int* active = (int*)(ws + OFF_ACT);
    int* total = (int*)(ws + OFF_TOT);
    uint32_t* ver = (uint32_t*)(ws + OFF_VER);
    uint32_t* bm0 = (uint32_t*)(ws + OFF_BM0);
    uint32_t* bm1 = (uint32_t*)(ws + OFF_BM1);

    hipMemsetAsync(ws + OFF_HX, 0, 1048576, stream);   // zero hist X+Y (1 MB)

    k_hist3<<<BB * SS * 4 * 2, 256, 0, stream>>>(xs, ys, histX, histY);
    k_shifts<<<BB * 2, 256, 0, stream>>>(histX, histY, blurk, aX, aY);

    // group 0: segments 2..9, 4 partials (init; no active check)
    k_bitmap_g<<<BB * 8 * 4, 256, 0, stream>>>(xs, ys, aX, aY, active,
                                               bm0, 2, 8, 4, 0);
    k_scan_g<<<BB, 256, 0, stream>>>(bm0, proceed, ver, total, active, 2, 8, 4, 1);

    // group 1: segments 10..31, 2 partials (active-gated; expected no-op).
    k_bitmap_g<<<BB * 22 * 2, 256, 0, stream>>>(xs, ys, aX, aY, active,
                                                bm1, 10, 22, 2, 1);
    k_scan_g<<<BB, 256, 0, stream>>>(bm1, proceed, ver, total, active, 10, 22, 2, 0);

    k_accum2<<<BB * 2, 1024, 0, stream>>>(xs, ys, aX, aY, proceed, out);
}

// Round 9
// 73.445 us; speedup vs baseline: 1.8603x; 1.1664x over previous
//
#include <hip/hip_runtime.h>
#include <cstdint>
#include <cstddef>

#define BB 16
#define NTOT 1048576
#define SS 32
#define SEG 32768
#define DIM 256
#define VW 512        // verifier bitmap words (16384 bits)

// ---------------- workspace layout (bytes), sizes derived explicitly ----------
// histX : BB*SS*256*4 = 524,288      [0, 524288)
// histY : 524,288                    [524288, 1048576)   dead after k_shifts
// BM0   : 16*8segs*4parts*512*4 = 1,048,576  [1048576, 2097152) dead after scan0
// BM1   : 16*22segs*2parts*512*4 = 1,441,792 [0, 1441792) aliases dead hist
// STG   : BB*2halves*16384 u32 = 2,097,152   [2138112, 4235264) packed-u16 image
#define OFF_HX   0u
#define OFF_HY   524288u
#define OFF_BM0  1048576u
#define OFF_BM1  0u
#define OFF_AX   2097152u            // BB*SS*4 = 2048
#define OFF_AY   2099200u            // 2048
#define OFF_PR   2101248u            // 2048
#define OFF_ACT  2103296u            // 1024
#define OFF_TOT  2104320u            // 1024
#define OFF_VER  2105344u            // BB*VW*4 = 32768
#define OFF_STG  2138112u            // 2 MB -> end 4,235,264 (~4.04 MB)

__device__ __forceinline__ int clamp255(int v) {
    return v < 0 ? 0 : (v > 255 ? 255 : v);
}

// ---------------- K1: conflict-free column histograms, one block per segment --
// grid = BB*SS*2arr = 1024 blocks x 256 thr. ph[256][32], column = t&31:
// bank = t%32 — data-independent 2-way (free). LDS-atomic pipe bound:
// ~1.4 lane-updates/cy/CU (measured wall, rounds 4-8) -> ~39 us. One block
// owns (b,s,arr) fully -> plain store, no memset, no global atomics.
// Also pre-zeros its 512-word slice of the accum staging buffer.
__global__ __launch_bounds__(256) void k_hist4(const int* __restrict__ xs,
                                               const int* __restrict__ ys,
                                               uint32_t* __restrict__ histX,
                                               uint32_t* __restrict__ histY,
                                               uint32_t* __restrict__ staging) {
    int blk = blockIdx.x;
    int arr = blk & 1;
    int s = (blk >> 1) & 31;
    int b = blk >> 6;
    int t = threadIdx.x;
    // zero staging: 1024 blocks x 512 words = 524288 words (2 MB)
    staging[(size_t)blk * 512 + t] = 0u;
    staging[(size_t)blk * 512 + 256 + t] = 0u;

    const int* src = arr ? ys : xs;
    uint32_t* dst = arr ? histY : histX;
    __shared__ uint32_t ph[256][32];      // 32 KB
    uint32_t* phl = (uint32_t*)ph;
#pragma unroll
    for (int i = 0; i < 32; ++i) phl[t + i * 256] = 0u;   // bank t%32, free
    __syncthreads();
    int c = t & 31;
    const int4* p4 = (const int4*)(src + (size_t)b * NTOT + (size_t)s * SEG);
#pragma unroll 8
    for (int i = 0; i < 32; ++i) {        // 32 * 256 * 4 = 32768 elements
        int4 v = p4[i * 256 + t];
        atomicAdd(&ph[v.x][c], 1u);
        atomicAdd(&ph[v.y][c], 1u);
        atomicAdd(&ph[v.z][c], 1u);
        atomicAdd(&ph[v.w][c], 1u);
    }
    __syncthreads();
    uint32_t sum = 0u;
#pragma unroll
    for (int j = 0; j < 32; ++j)
        sum += ph[t][(j + t) & 31];       // rotated read, conflict-free
    dst[(size_t)(b * SS + s) * 256 + t] = sum;
}

// ---------------- K2: wave-parallel stats -> clip -> blur -> centroid -> shifts
__global__ __launch_bounds__(256) void k_shifts(const uint32_t* __restrict__ histX,
                                                const uint32_t* __restrict__ histY,
                                                const float* __restrict__ blurk,
                                                int* __restrict__ alignedX,
                                                int* __restrict__ alignedY) {
    int blk = blockIdx.x;          // 0..31 : b*2 + axis
    int b = blk >> 1, axis = blk & 1;
    const uint32_t* hist = (axis == 0 ? histX : histY) + (size_t)b * SS * DIM;
    int* out = (axis == 0 ? alignedX : alignedY) + b * SS;

    __shared__ float vals[SS][DIM];
    __shared__ double wsq[4];
    __shared__ float mrow[SS];
    int t = threadIdx.x;
    int w = t >> 6, lane = t & 63;
    int c0 = lane << 2;                       // 4 columns per lane

    double lsq = 0.0;
    for (int r = w; r < SS; r += 4) {
        uint4 u = *(const uint4*)(hist + r * DIM + c0);
        float v0 = (float)u.x, v1 = (float)u.y, v2 = (float)u.z, v3 = (float)u.w;
        vals[r][c0 + 0] = v0; vals[r][c0 + 1] = v1;
        vals[r][c0 + 2] = v2; vals[r][c0 + 3] = v3;
        double d0 = (double)v0 - 128.0, d1 = (double)v1 - 128.0;
        double d2 = (double)v2 - 128.0, d3 = (double)v3 - 128.0;
        lsq += d0 * d0 + d1 * d1 + d2 * d2 + d3 * d3;
    }
    for (int o = 32; o > 0; o >>= 1) lsq += __shfl_xor(lsq, o, 64);
    if (lane == 0) wsq[w] = lsq;
    __syncthreads();
    float s2 = (float)(wsq[0] + wsq[1] + wsq[2] + wsq[3]);   // exact integer
    float sd = sqrtf(s2 / 8191.0f);                          // ddof=1, pooled
    float thr = 128.0f + 3.0f * sd;

    float k00 = blurk[0], k01 = blurk[1], k02 = blurk[2];
    float k10 = blurk[3], k11 = blurk[4], k12 = blurk[5];
    float k20 = blurk[6], k21 = blurk[7], k22 = blurk[8];

#define V(r, c) fminf(vals[r][c], thr)
    for (int s = w; s < SS; s += 4) {
        double dot = 0.0;
#pragma unroll
        for (int j = 0; j < 4; ++j) {
            int c = c0 + j;
            int cm = c - 1, cp = c + 1;
            bool cml = (cm >= 0), cpl = (cp < DIM);
            float bsum = 0.0f;
            if (s - 1 >= 0) {
                if (cml) bsum += k00 * V(s - 1, cm);
                bsum += k01 * V(s - 1, c);
                if (cpl) bsum += k02 * V(s - 1, cp);
            }
            if (cml) bsum += k10 * V(s, cm);
            bsum += k11 * V(s, c);
            if (cpl) bsum += k12 * V(s, cp);
            if (s + 1 < SS) {
                if (cml) bsum += k20 * V(s + 1, cm);
                bsum += k21 * V(s + 1, c);
                if (cpl) bsum += k22 * V(s + 1, cp);
            }
            dot += (double)bsum * (double)c;
        }
        for (int o = 32; o > 0; o >>= 1) dot += __shfl_xor(dot, o, 64);
        if (lane == 0) mrow[s] = (float)(dot / 32768.0);
    }
#undef V
    __syncthreads();

    if (t < SS) {
        float start = mrow[2];                    // START = 2
        float a = mrow[t] - start;
        float c = 128.0f - start;                 // dimlen//2 - start
        out[t] = (int)rintf(a - c);               // round half-to-even
    }
}

// ---------------- K3: partial verifier bitmaps for a segment group -------------
__global__ __launch_bounds__(256) void k_bitmap_g(const int* __restrict__ xs,
                                                  const int* __restrict__ ys,
                                                  const int* __restrict__ aX,
                                                  const int* __restrict__ aY,
                                                  const int* __restrict__ active,
                                                  uint32_t* __restrict__ bmp,
                                                  int first_seg, int nseg,
                                                  int parts, int check_active) {
    int blk = blockIdx.x;
    int p = blk % parts;
    int sl = (blk / parts) % nseg;
    int b = blk / (parts * nseg);
    if (check_active && !active[b]) return;
    int s = first_seg + sl;
    int shx = aX[b * SS + s];
    int shy = aY[b * SS + s];
    __shared__ uint32_t bm[VW];
    int t = threadIdx.x;
    bm[t] = 0u; bm[t + 256] = 0u;
    __syncthreads();
    size_t base = (size_t)b * NTOT + (size_t)s * SEG + (size_t)p * (SEG / parts);
    const int4* x4 = (const int4*)(xs + base);
    const int4* y4 = (const int4*)(ys + base);
    int iters = SEG / (parts * 1024);
    for (int i = 0; i < iters; ++i) {
        int4 xv = x4[i * 256 + t];
        int4 yv = y4[i * 256 + t];
#define DOV(xc, yc) { int xf = clamp255((xc) - shx); int yf = clamp255((yc) - shy); \
                      int iv = (xf >> 1) + ((yf >> 1) << 7); \
                      atomicOr(&bm[iv >> 5], 1u << (iv & 31)); }
        DOV(xv.x, yv.x) DOV(xv.y, yv.y) DOV(xv.z, yv.z) DOV(xv.w, yv.w)
#undef DOV
    }
    __syncthreads();
    uint32_t* outp = bmp + ((size_t)(b * nseg + sl) * parts + p) * VW;
    outp[t] = bm[t];
    outp[t + 256] = bm[t + 256];
}

// ---------------- K4: sequential verifier scan over one group ------------------
__global__ __launch_bounds__(256) void k_scan_g(const uint32_t* __restrict__ bmp,
                                                int* __restrict__ proceed,
                                                uint32_t* __restrict__ ver_state,
                                                int* __restrict__ total_state,
                                                int* __restrict__ active_state,
                                                int first_seg, int nseg,
                                                int parts, int do_init) {
    int b = blockIdx.x;                   // 0..15
    int t = threadIdx.x;
    __shared__ uint32_t ver[VW];
    __shared__ int wred[4];
    __shared__ int sh_flag;
    __shared__ int sh_total;

    for (int i = t; i < nseg; i += 256) proceed[b * SS + first_seg + i] = 0;

    int active = do_init ? 1 : active_state[b];
    if (!active) {
        if (t == 0) active_state[b] = 0;
        return;
    }

    const uint32_t* base = bmp + (size_t)b * nseg * parts * VW;
    int wid = t >> 6, lane = t & 63;
    int start_local;

    if (do_init) {
        uint32_t w0 = 0, w1 = 0;
        for (int p = 0; p < parts; ++p) {
            w0 |= base[(size_t)p * VW + t];
            w1 |= base[(size_t)p * VW + t + 256];
        }
        ver[t] = w0; ver[t + 256] = w1;
        int c = __popc(w0) + __popc(w1);
        for (int o = 32; o > 0; o >>= 1) c += __shfl_down(c, o, 64);
        if (lane == 0) wred[wid] = c;
        __syncthreads();
        if (t == 0) {
            sh_total = wred[0] + wred[1] + wred[2] + wred[3];
            proceed[b * SS + first_seg] = 1;   // START segment
        }
        start_local = 1;
    } else {
        ver[t] = ver_state[(size_t)b * VW + t];
        ver[t + 256] = ver_state[(size_t)b * VW + t + 256];
        if (t == 0) sh_total = total_state[b];
        start_local = 0;
    }
    __syncthreads();

    for (int sl = start_local; sl < nseg; ++sl) {
        uint32_t w0 = 0, w1 = 0;
        for (int p = 0; p < parts; ++p) {
            w0 |= base[(size_t)(sl * parts + p) * VW + t];
            w1 |= base[(size_t)(sl * parts + p) * VW + t + 256];
        }
        int c = __popc(w0 & ~ver[t]) + __popc(w1 & ~ver[t + 256]);
        for (int o = 32; o > 0; o >>= 1) c += __shfl_down(c, o, 64);
        if (lane == 0) wred[wid] = c;
        __syncthreads();
        if (t == 0) {
            int newly = wred[0] + wred[1] + wred[2] + wred[3];
            int total = sh_total + newly;
            float ratio = (float)newly / (float)total;
            int f = (ratio >= 0.01f) ? 1 : 0;
            sh_flag = f;
            if (f) {
                sh_total = total;
                proceed[b * SS + first_seg + sl] = 1;
            }
        }
        __syncthreads();
        if (!sh_flag) { active = 0; break; }
        ver[t] |= w0;
        ver[t + 256] |= w1;
        __syncthreads();
    }

    ver_state[(size_t)b * VW + t] = ver[t];
    ver_state[(size_t)b * VW + t + 256] = ver[t + 256];
    if (t == 0) {
        total_state[b] = sh_total;
        active_state[b] = active;
    }
}

// ---------------- K5: (b, half, quarter) LDS accumulation + sparse merge -------
// grid = BB*2*4 = 128 blocks x 1024 thr. Block (b,half,p) processes elements
// [p*8192,(p+1)*8192) of every proceeding segment, counts its y-half in a
// 64 KB packed-u16 LDS image, then atomicAdds NONZERO words into the 2 MB
// global staging image (zeroed by k_hist4). Spreads the LDS-atomic wall over
// 128 CUs (was 32) -> ~4x faster accumulation.
__global__ __launch_bounds__(1024) void k_accum6(const int* __restrict__ xs,
                                                 const int* __restrict__ ys,
                                                 const int* __restrict__ aX,
                                                 const int* __restrict__ aY,
                                                 const int* __restrict__ proceed,
                                                 uint32_t* __restrict__ staging) {
    int blk = blockIdx.x;
    int p = blk & 3, half = (blk >> 2) & 1, b = blk >> 3;
    __shared__ uint32_t acc[16384];                   // 32768 u16 cells (128x256)
    int t = threadIdx.x;
    for (int i = t; i < 16384; i += 1024) acc[i] = 0u;
    __syncthreads();
    int ybase = half << 7;
    for (int s = 2; s < SS; ++s) {
        if (!proceed[b * SS + s]) continue;
        int shx = aX[b * SS + s];
        int shy = aY[b * SS + s];
        size_t base = (size_t)b * NTOT + (size_t)s * SEG + (size_t)p * 8192;
        const int4* x4 = (const int4*)(xs + base);
        const int4* y4 = (const int4*)(ys + base);
#pragma unroll
        for (int i = 0; i < 2; ++i) {     // 2 * 1024 * 4 = 8192 elements
            int4 xv = x4[i * 1024 + t];
            int4 yv = y4[i * 1024 + t];
#define DOC(xc, yc) { int xf = clamp255((xc) - shx); int yf = clamp255((yc) - shy); \
                      if ((yf >> 7) == half) { \
                          int cell = xf + ((yf - ybase) << 8); \
                          atomicAdd(&acc[cell >> 1], 1u << ((cell & 1) << 4)); } }
            DOC(xv.x, yv.x) DOC(xv.y, yv.y) DOC(xv.z, yv.z) DOC(xv.w, yv.w)
#undef DOC
        }
    }
    __syncthreads();
    uint32_t* stg = staging + (size_t)b * 32768 + ((size_t)half << 14);
    for (int i = t; i < 16384; i += 1024) {
        uint32_t w = acc[i];
        if (w) atomicAdd(&stg[i], w);     // packed u16 pair: no cross-carry
    }
}

// ---------------- K6: staging (packed u16) -> float output ---------------------
// 512 blocks x 1024 thr, one u32 word -> one float2. Covers ALL cells.
__global__ __launch_bounds__(1024) void k_convert(const uint32_t* __restrict__ staging,
                                                  float* __restrict__ out) {
    int g = blockIdx.x * 1024 + threadIdx.x;          // 0..524287
    uint32_t w = staging[g];
    ((float2*)out)[g] = make_float2((float)(w & 0xFFFFu), (float)(w >> 16));
}

extern "C" void kernel_launch(void* const* d_in, const int* in_sizes, int n_in,
                              void* d_out, int out_size, void* d_ws, size_t ws_size,
                              hipStream_t stream) {
    const int* xs = (const int*)d_in[0];
    const int* ys = (const int*)d_in[1];
    const float* blurk = (const float*)d_in[2];
    float* out = (float*)d_out;

    uint8_t* ws = (uint8_t*)d_ws;
    uint32_t* histX = (uint32_t*)(ws + OFF_HX);
    uint32_t* histY = (uint32_t*)(ws + OFF_HY);
    int* aX = (int*)(ws + OFF_AX);
    int* aY = (int*)(ws + OFF_AY);
    int* proceed = (int*)(ws + OFF_PR);
    int* active = (int*)(ws + OFF_ACT);
    int* total = (int*)(ws + OFF_TOT);
    uint32_t* ver = (uint32_t*)(ws + OFF_VER);
    uint32_t* bm0 = (uint32_t*)(ws + OFF_BM0);
    uint32_t* bm1 = (uint32_t*)(ws + OFF_BM1);
    uint32_t* staging = (uint32_t*)(ws + OFF_STG);

    k_hist4<<<BB * SS * 2, 256, 0, stream>>>(xs, ys, histX, histY, staging);
    k_shifts<<<BB * 2, 256, 0, stream>>>(histX, histY, blurk, aX, aY);

    // group 0: segments 2..9, 4 partials (init; no active check)
    k_bitmap_g<<<BB * 8 * 4, 256, 0, stream>>>(xs, ys, aX, aY, active,
                                               bm0, 2, 8, 4, 0);
    k_scan_g<<<BB, 256, 0, stream>>>(bm0, proceed, ver, total, active, 2, 8, 4, 1);

    // group 1: segments 10..31, 2 partials (active-gated; expected no-op)
    k_bitmap_g<<<BB * 22 * 2, 256, 0, stream>>>(xs, ys, aX, aY, active,
                                                bm1, 10, 22, 2, 1);
    k_scan_g<<<BB, 256, 0, stream>>>(bm1, proceed, ver, total, active, 10, 22, 2, 0);

    k_accum6<<<BB * 2 * 4, 1024, 0, stream>>>(xs, ys, aX, aY, proceed, staging);
    k_convert<<<512, 1024, 0, stream>>>(staging, out);
}